// Round 10
// baseline (30012.906 us; speedup 1.0000x reference)
//
#include <hip/hip_runtime.h>
#include <stdint.h>

#define T_STEPS 8192
#define HID     1024
#define IN_F    2048
#define N3H     3072   // 3*HID
#define NXCD    8

// ---------------------------------------------------------------------------
// r9/r10: hierarchical exchange. Evidence r6/r7/r8: step time scales with
// scoped (LLC) probe pressure -- 256 wg sweeps contend with producer stores
// on the same lines. Topology:
//   producers --sc0sc1--> home[2][1024] (LLC)   [1 store per j per step]
//   8 relay wgs (one per XCD, atomicCAS-elected via HW_REG_XCC_ID) poll home
//   at the LLC (only 8 sweeps) and copy the tagged vector verbatim to
//   xbuf[xcd][2][1024] with sc0-only stores (XCD-local L2).
//   ~31 consumer wgs per XCD poll xbuf[xcd] with sc0-only loads (L1-bypass,
//   L2-served, ~200-300cy RTT, zero LLC pressure).
// Tag protocol unchanged: low 2 mantissa bits = step&3; double-buffered;
// full-vector detection bounds skew <2 steps; relay copy preserves tags, so
// all r6 proofs carry (relay = one more observer; xbuf overwrite of step i
// requires home h^{i+2}, which requires every wg past step i+1). Word-
// granular republish is fine: every word carries its own tag; inter-word
// tearing was always allowed.
// h_0 = 0.0f with tag 0 == 0x0 -> zero-init of home AND xbuf is step-0 data.
//
// SAFETY VALVE (placement): sc0-only polling requires consumer co-XCD with
// its relay (else its own L2 caches a stale line forever -> hang). At the
// first non-trivial step (i>=1) each consumer wave validates with a bounded
// 4096-probe local spin; success latches local mode permanently (placement
// is static), timeout latches home-polling (sc0sc1) permanently. Worst case
// = r6 behavior + ~0.5ms. No hang possible.
//
// Probe discipline (r2-r5 lessons): every probe is ONE fused asm
// (load + s_waitcnt vmcnt(0)) -- no split issue/wait, no in-flight load with
// compiler-dead destination; all poll exits wave-uniform (__all). Stores
// take only SCALAR u32 asm inputs (hipcc can't handle uint4 asm operands).
// ---------------------------------------------------------------------------
__global__ void init_exchange(unsigned int* p, int n) {
    int i = blockIdx.x * blockDim.x + threadIdx.x;
    if (i < n) p[i] = 0u;
}

// fused LLC probe (system scope: sc0 sc1 bypasses L1+L2)
__device__ __forceinline__ uint4 probe_llc(const unsigned int* p) {
    uint4 r;
    asm volatile("global_load_dwordx4 %0, %1, off sc0 sc1\n\t"
                 "s_waitcnt vmcnt(0)"
                 : "=v"(r) : "v"(p) : "memory");
    return r;
}
// fused XCD-local probe (sc0 only: bypass L1, served by this XCD's L2)
__device__ __forceinline__ uint4 probe_l2(const unsigned int* p) {
    uint4 r;
    asm volatile("global_load_dwordx4 %0, %1, off sc0\n\t"
                 "s_waitcnt vmcnt(0)"
                 : "=v"(r) : "v"(p) : "memory");
    return r;
}
// XCD-local word store (sc0: bypass L1, lands in this XCD's L2)
__device__ __forceinline__ void store_l2(unsigned int* p, unsigned int v) {
    asm volatile("global_store_dword %0, %1, off sc0"
                 :: "v"(p), "v"(v) : "memory");
}
__device__ __forceinline__ void store_scoped(unsigned int* p, unsigned int v) {
    asm volatile("global_store_dword %0, %1, off sc0 sc1"
                 :: "v"(p), "v"(v) : "memory");
}
__device__ __forceinline__ int tag_ok(const uint4& v, unsigned int w) {
    return (((v.x & 3u) == w) & ((v.y & 3u) == w) &
            ((v.z & 3u) == w) & ((v.w & 3u) == w));
}

// ---------------------------------------------------------------------------
// Phase 1: gi[t, j'] = x[t] . w_ih[j'] + b_ih[j']  (unchanged, ~1.4 ms)
// ---------------------------------------------------------------------------
#define GBM 64
#define GBN 64
#define GBK 32

__global__ __launch_bounds__(256) void gi_gemm(
    const float* __restrict__ feat,   // [8192][2048]
    const float* __restrict__ rew,    // [8192]
    const float* __restrict__ w_ih,   // [3072][2049]
    const float* __restrict__ b_ih,   // [3072]
    float* __restrict__ gi)           // [8192][3072]
{
    __shared__ float As[GBK][GBM + 4];
    __shared__ float Bs[GBK][GBN + 4];

    const int tid = threadIdx.x;
    const int n0 = blockIdx.x * GBN;
    const int t0 = blockIdx.y * GBM;
    const int tx = tid & 15, ty = tid >> 4;
    const int lr = tid >> 3;
    const int lc = (tid & 7) * 4;

    float acc[4][4] = {{0.f}};

    for (int k0 = 0; k0 < IN_F; k0 += GBK) {
#pragma unroll
        for (int hh = 0; hh < 2; hh++) {
            const int r = lr + 32 * hh;
            const float4 a = *(const float4*)(feat + (size_t)(t0 + r) * IN_F + k0 + lc);
            As[lc + 0][r] = a.x; As[lc + 1][r] = a.y;
            As[lc + 2][r] = a.z; As[lc + 3][r] = a.w;
            const float* brow = w_ih + (size_t)(n0 + r) * (IN_F + 1) + k0 + lc;
            Bs[lc + 0][r] = brow[0]; Bs[lc + 1][r] = brow[1];
            Bs[lc + 2][r] = brow[2]; Bs[lc + 3][r] = brow[3];
        }
        __syncthreads();
#pragma unroll
        for (int kk = 0; kk < GBK; kk++) {
            const float4 a = *(const float4*)&As[kk][ty * 4];
            const float4 b = *(const float4*)&Bs[kk][tx * 4];
            acc[0][0] += a.x * b.x; acc[0][1] += a.x * b.y; acc[0][2] += a.x * b.z; acc[0][3] += a.x * b.w;
            acc[1][0] += a.y * b.x; acc[1][1] += a.y * b.y; acc[1][2] += a.y * b.z; acc[1][3] += a.y * b.w;
            acc[2][0] += a.z * b.x; acc[2][1] += a.z * b.y; acc[2][2] += a.z * b.z; acc[2][3] += a.z * b.w;
            acc[3][0] += a.w * b.x; acc[3][1] += a.w * b.y; acc[3][2] += a.w * b.z; acc[3][3] += a.w * b.w;
        }
        __syncthreads();
    }

    const int m = t0 + ty * 4;
    const int n = n0 + tx * 4;
    float wlast[4], bi[4];
#pragma unroll
    for (int c = 0; c < 4; c++) {
        wlast[c] = w_ih[(size_t)(n + c) * (IN_F + 1) + IN_F];
        bi[c]    = b_ih[n + c];
    }
#pragma unroll
    for (int r = 0; r < 4; r++) {
        const float rwv = rew[m + r];
        float4 v;
        v.x = acc[r][0] + rwv * wlast[0] + bi[0];
        v.y = acc[r][1] + rwv * wlast[1] + bi[1];
        v.z = acc[r][2] + rwv * wlast[2] + bi[2];
        v.w = acc[r][3] + rwv * wlast[3] + bi[3];
        *(float4*)(gi + (size_t)(m + r) * N3H + n) = v;
    }
}

// ---------------------------------------------------------------------------
// Phase 2: persistent GRU scan, relay topology. 256 wgs x 256 threads; wg g
// owns j in [4g,4g+4), one j per wave. Weights in static LDS (48 KB); h_lds
// double-buffered -> ONE __syncthreads per step (r6 proof). Own h[j] carried
// in a register (exact). Gates computed redundantly on all lanes after a
// shfl_xor butterfly; producer store = one lane-0 issue to home.
// ---------------------------------------------------------------------------
__global__ __launch_bounds__(256, 2) void gru_scan(
    const float* __restrict__ gi,     // [8192][3072]
    const float* __restrict__ w_hh,   // [3072][1024]
    const float* __restrict__ b_hh,   // [3072]
    unsigned int* home,               // [2][1024] tagged fp32 (LLC)
    unsigned int* xbuf,               // [8][2][1024] tagged fp32 (per-XCD L2)
    unsigned int* claim,              // [8] relay election slots
    float* __restrict__ out)          // [1024]
{
    __shared__ float4 w_lds[3][4][HID / 4];  // 48 KB
    __shared__ float4 h_lds[2][HID / 4];     // 8 KB, double-buffered
    __shared__ unsigned int s_flags;

    const int tid  = threadIdx.x;
    const int g    = blockIdx.x;      // 0..255
    const int wave = tid >> 6;
    const int lane = tid & 63;
    const int myj  = g * 4 + wave;

    unsigned int xcd;
    asm volatile("s_getreg_b32 %0, hwreg(HW_REG_XCC_ID)" : "=s"(xcd));
    xcd &= (NXCD - 1);

    if (tid == 0) {
        unsigned int old = atomicCAS(&claim[xcd], 0u, 1u + (unsigned int)g);
        s_flags = (old == 0u ? 1u : 0u) | (xcd << 8);
    }

#pragma unroll
    for (int r = 0; r < 12; r++) {
        const int gate = r >> 2, jl = r & 3;
        const float4* src = (const float4*)(w_hh + (size_t)(gate * HID + g * 4 + jl) * HID);
        w_lds[gate][jl][tid] = src[tid];
    }
    const float b_r = b_hh[myj];
    const float b_z = b_hh[HID + myj];
    const float b_n = b_hh[2 * HID + myj];
    __syncthreads();

    const bool is_relay = (s_flags & 1u) != 0u;
    const unsigned int myx = (s_flags >> 8) & (NXCD - 1);

    bool local_ok = false;   // latched at i>=1 on first local success
    bool use_home = false;   // latched on local timeout (placement fallback)
    float hj = 0.f;          // own h[j], exact

    for (int i = 0; i < T_STEPS; i++) {
        const int t = T_STEPS - 1 - i;
        const unsigned int want = (unsigned int)(i & 3);
        const unsigned int* hb = home + (size_t)(i & 1) * HID + tid * 4;
        unsigned int* xb = xbuf + ((size_t)myx * 2 + (size_t)(i & 1)) * HID + tid * 4;

        // gi prefetch: uniform-address broadcast loads, drained under poll
        const float* girow = gi + (size_t)t * N3H + myj;
        const float gi_r = girow[0];
        const float gi_z = girow[HID];
        const float gi_n = girow[2 * HID];

        uint4 v;
        if (is_relay) {
            // LLC detect (one of only 8 pollers), then local re-publish
            for (;;) {
                v = probe_llc(hb);
                if (__all(tag_ok(v, want))) break;
            }
            store_l2(xb + 0, v.x);
            store_l2(xb + 1, v.y);
            store_l2(xb + 2, v.z);
            store_l2(xb + 3, v.w);
        } else if (!use_home) {
            if (local_ok) {
                for (;;) {
                    v = probe_l2(xb);
                    if (__all(tag_ok(v, want))) break;
                }
            } else {
                int got = 0;
                for (int tries = 0; tries < 4096; ++tries) {
                    v = probe_l2(xb);
                    if (__all(tag_ok(v, want))) { got = 1; break; }
                }
                if (got) {
                    if (i >= 1) local_ok = true;  // i==0 succeeds trivially
                } else {
                    use_home = true;              // misplaced: permanent fallback
                }
            }
        }
        if (use_home && !is_relay) {
            for (;;) {
                v = probe_llc(hb);
                if (__all(tag_ok(v, want))) break;
            }
        }

        float4 hv;
        hv.x = __uint_as_float(v.x);
        hv.y = __uint_as_float(v.y);
        hv.z = __uint_as_float(v.z);
        hv.w = __uint_as_float(v.w);
        h_lds[i & 1][tid] = hv;
        __syncthreads();   // the ONE per-step barrier (full fence)

        // wave `wave` computes the 3 recurrent dots for j = myj
        float ar = 0.f, az = 0.f, an = 0.f;
        const float4* hbuf = h_lds[i & 1];
        const float4* wr = w_lds[0][wave];
        const float4* wz = w_lds[1][wave];
        const float4* wn = w_lds[2][wave];
#pragma unroll
        for (int m4 = 0; m4 < 4; m4++) {
            const int idx = lane + 64 * m4;
            const float4 h4 = hbuf[idx];
            const float4 r4 = wr[idx];
            const float4 z4 = wz[idx];
            const float4 n4 = wn[idx];
            ar += h4.x * r4.x + h4.y * r4.y + h4.z * r4.z + h4.w * r4.w;
            az += h4.x * z4.x + h4.y * z4.y + h4.z * z4.z + h4.w * z4.w;
            an += h4.x * n4.x + h4.y * n4.y + h4.z * n4.z + h4.w * n4.w;
        }
#pragma unroll
        for (int off = 32; off > 0; off >>= 1) {
            ar += __shfl_xor(ar, off);
            az += __shfl_xor(az, off);
            an += __shfl_xor(an, off);
        }

        // gates redundantly on all lanes; producer store = ONE lane issue
        const float r = 1.f / (1.f + __expf(-(gi_r + ar + b_r)));
        const float z = 1.f / (1.f + __expf(-(gi_z + az + b_z)));
        const float n = tanhf(gi_n + r * (an + b_n));
        const float hnew = (1.f - z) * n + z * hj;
        hj = hnew;

        if (i == T_STEPS - 1) {
            if (lane == 0) out[myj] = hnew;
        } else {
            const unsigned int pk =
                (__float_as_uint(hnew) & ~3u) | (unsigned int)((i + 1) & 3);
            if (lane == 0)
                store_scoped(home + (size_t)((i + 1) & 1) * HID + myj, pk);
        }
    }
}

// ---------------------------------------------------------------------------
extern "C" void kernel_launch(void* const* d_in, const int* in_sizes, int n_in,
                              void* d_out, int out_size, void* d_ws, size_t ws_size,
                              hipStream_t stream) {
    const float* feat = (const float*)d_in[0];  // [8192,2048]
    const float* rew  = (const float*)d_in[1];  // [8192]
    const float* w_ih = (const float*)d_in[2];  // [3072,2049]
    const float* w_hh = (const float*)d_in[3];  // [3072,1024]
    const float* b_ih = (const float*)d_in[4];  // [3072]
    const float* b_hh = (const float*)d_in[5];  // [3072]
    float* out = (float*)d_out;                 // [1024]

    float* gi = (float*)d_ws;                                       // 96 MB
    unsigned int* home  = (unsigned int*)((char*)d_ws + (size_t)T_STEPS * N3H * sizeof(float));
    unsigned int* xbuf  = home + 2 * HID;            // [8][2][1024] = 64 KB
    unsigned int* claim = xbuf + NXCD * 2 * HID;     // [8]
    const int n_zero = 2 * HID + NXCD * 2 * HID + NXCD;  // home+xbuf+claim

    hipLaunchKernelGGL(init_exchange, dim3((n_zero + 255) / 256), dim3(256), 0, stream,
                       home, n_zero);
    hipLaunchKernelGGL(gi_gemm, dim3(N3H / GBN, T_STEPS / GBM), dim3(256), 0, stream,
                       feat, rew, w_ih, b_ih, gi);
    hipLaunchKernelGGL(gru_scan, dim3(256), dim3(256), 0, stream,
                       gi, w_hh, b_hh, home, xbuf, claim, out);
}